// Round 1
// baseline (3430.206 us; speedup 1.0000x reference)
//
#include <hip/hip_runtime.h>
#include <hip/hip_bf16.h>

#define TT 512
#define BB 256
#define SS 256
#define AA 8
#define DD 64

typedef unsigned short ushort_t;
typedef unsigned long long u64_t;
typedef __bf16 bf16x8 __attribute__((ext_vector_type(8)));
typedef float  f32x4  __attribute__((ext_vector_type(4)));

__device__ __forceinline__ ushort_t f2bf(float x) {
  union { float f; unsigned u; } v; v.f = x;
  unsigned r = (v.u + 0x7FFFu + ((v.u >> 16) & 1u)) >> 16;
  return (ushort_t)r;
}
__device__ __forceinline__ float bf2f(unsigned h) {
  return __uint_as_float((h & 0xFFFFu) << 16);
}
__device__ __forceinline__ u64_t ld_u64(const u64_t* p) {
  return __hip_atomic_load(p, __ATOMIC_RELAXED, __HIP_MEMORY_SCOPE_AGENT);
}
__device__ __forceinline__ unsigned ld_u32(const unsigned* p) {
  return __hip_atomic_load(p, __ATOMIC_RELAXED, __HIP_MEMORY_SCOPE_AGENT);
}
__device__ __forceinline__ void st_u32(unsigned* p, unsigned v) {
  __hip_atomic_store(p, v, __ATOMIC_RELAXED, __HIP_MEMORY_SCOPE_AGENT);
}
// release fence: wave-wide drain of all outstanding vector-memory stores to L2.
// A flag store issued after this is visible only after all prior data stores.
__device__ __forceinline__ void release_fence() {
  asm volatile("s_waitcnt vmcnt(0)" ::: "memory");
}

// ---------------- prologue: per-state Gaussian params ----------------
__global__ __launch_bounds__(64) void k_params(const float* __restrict__ mu,
                                               const float* __restrict__ lv,
                                               float* __restrict__ A1, float* __restrict__ A2,
                                               float* __restrict__ Cs) {
  const float LOG2PI = 1.8378770664093453f;
  int s = blockIdx.x, d = threadIdx.x;
  float l = lv[s * DD + d], m_ = mu[s * DD + d];
  float inv = __expf(-l);
  A1[s * DD + d] = inv;
  A2[s * DD + d] = m_ * inv;
  float part = m_ * m_ * inv + l;
  #pragma unroll
  for (int o = 32; o >= 1; o >>= 1) part += __shfl_down(part, o);
  if (d == 0) Cs[s] = part + (float)DD * LOG2PI;
}

// ---------------- prologue: log_softmax of s0_logits ----------------
__global__ __launch_bounds__(256) void k_pi0(const float* __restrict__ s0, float* __restrict__ lp0) {
  __shared__ float red[4];
  int tid = threadIdx.x, ln = tid & 63, wv = tid >> 6;
  float v = s0[tid];
  float m = v;
  #pragma unroll
  for (int o = 32; o >= 1; o >>= 1) m = fmaxf(m, __shfl_xor(m, o));
  if (ln == 0) red[wv] = m;
  __syncthreads();
  m = fmaxf(fmaxf(red[0], red[1]), fmaxf(red[2], red[3]));
  __syncthreads();
  float e = __expf(v - m);
  float s = e;
  #pragma unroll
  for (int o = 32; o >= 1; o >>= 1) s += __shfl_xor(s, o);
  if (ln == 0) red[wv] = s;
  __syncthreads();
  s = red[0] + red[1] + red[2] + red[3];
  lp0[tid] = v - m - __logf(s);
}

// ---------------- prologue: softmax(w_logits) -> bf16 MFMA B-fragment layouts ----------------
__global__ __launch_bounds__(256) void k_trans(const float* __restrict__ wl,
                                               ushort_t* __restrict__ Wf, ushort_t* __restrict__ Wb) {
  int tid = threadIdx.x;
  int rl = tid >> 5, l = tid & 31;
  int row = blockIdx.x * 8 + rl;      // row = a*256 + i
  int a = row >> 8, i = row & 255;
  const float* src = wl + (size_t)row * 256 + l * 8;
  float v[8];
  *reinterpret_cast<float4*>(&v[0]) = *reinterpret_cast<const float4*>(src);
  *reinterpret_cast<float4*>(&v[4]) = *reinterpret_cast<const float4*>(src + 4);
  float m = v[0];
  #pragma unroll
  for (int k = 1; k < 8; ++k) m = fmaxf(m, v[k]);
  #pragma unroll
  for (int o = 16; o >= 1; o >>= 1) m = fmaxf(m, __shfl_xor(m, o, 32));
  float s = 0.f;
  #pragma unroll
  for (int k = 0; k < 8; ++k) { v[k] = __expf(v[k] - m); s += v[k]; }
  #pragma unroll
  for (int o = 16; o >= 1; o >>= 1) s += __shfl_xor(s, o, 32);
  float inv = 1.0f / s;
  #pragma unroll
  for (int k = 0; k < 8; ++k) {
    int j = l * 8 + k;
    ushort_t h = f2bf(v[k] * inv);
    size_t fi = (size_t)((a * 8 + (i >> 5)) * 16 + (j >> 4));
    Wf[fi * 512 + (((i >> 3) & 3) * 16 + (j & 15)) * 8 + (i & 7)] = h;
    size_t bi = (size_t)((a * 8 + (j >> 5)) * 16 + (i >> 4));
    Wb[bi * 512 + (((j >> 3) & 3) * 16 + (i & 15)) * 8 + (j & 7)] = h;
  }
}

// ---------------- logp_x [T,B,S] in fp32 + per-row max ----------------
__global__ __launch_bounds__(256) void k_logp(const float* __restrict__ x,
    const float* __restrict__ A1, const float* __restrict__ A2,
    const float* __restrict__ Cs, float* __restrict__ logp, float* __restrict__ Mmax) {
  __shared__ float sA1[64][64];
  __shared__ float sA2[64][64];
  int tid = threadIdx.x;
  int row = tid >> 3, dg = tid & 7;
  size_t row0 = (size_t)blockIdx.x * 32;
  const float* xp = x + (row0 + row) * DD + dg * 8;
  float xv[8];
  *reinterpret_cast<float4*>(&xv[0]) = *reinterpret_cast<const float4*>(xp);
  *reinterpret_cast<float4*>(&xv[4]) = *reinterpret_cast<const float4*>(xp + 4);
  float m = -3.0e38f;
  float* orow = logp + (row0 + row) * SS;
  for (int st = 0; st < 4; ++st) {
    __syncthreads();
    #pragma unroll
    for (int k = 0; k < 4; ++k) {
      int flat = k * 1024 + tid * 4;
      int sr = flat >> 6, sc = flat & 63;
      *reinterpret_cast<float4*>(&sA1[sr][sc]) = *reinterpret_cast<const float4*>(&A1[(size_t)(st * 64 + sr) * 64 + sc]);
      *reinterpret_cast<float4*>(&sA2[sr][sc]) = *reinterpret_cast<const float4*>(&A2[(size_t)(st * 64 + sr) * 64 + sc]);
    }
    __syncthreads();
    for (int s = 0; s < 64; ++s) {
      float acc = 0.f;
      #pragma unroll
      for (int j = 0; j < 8; ++j) {
        float t1 = __builtin_fmaf(sA1[s][dg * 8 + j], xv[j], -2.0f * sA2[s][dg * 8 + j]);
        acc = __builtin_fmaf(t1, xv[j], acc);
      }
      acc += __shfl_xor(acc, 1, 8);
      acc += __shfl_xor(acc, 2, 8);
      acc += __shfl_xor(acc, 4, 8);
      float lp = -0.5f * (acc + Cs[st * 64 + s]);
      m = fmaxf(m, lp);
      if (((s ^ dg) & 7) == 0) __builtin_nontemporal_store(lp, orow + st * 64 + s);
    }
  }
  if (dg == 0) Mmax[row0 + row] = m;
}

// ---------------- recursion: flag-release mailbox pipeline ----------------
// amb/bmb: [2 parity][16 grp][16 row][256 col] u32 = (tag16 | bf16 payload)  (data, not polled)
// cmb/rmb: [2 parity][16 grp][16 row][8 wg]   u32 = (tag16 | bf16 row-partial-sum)  (flag+sum, polled)
// Publisher: data stores -> s_waitcnt vmcnt(0) (release) -> tagged flag store.
// Consumer: light poll on 128 flag words only; on pass, bulk-read data once.
__global__ __launch_bounds__(256, 1) void k_recur(
    const float* __restrict__ a_in, const float* __restrict__ mask,
    float* __restrict__ out, float* __restrict__ beta,
    const float* __restrict__ logp, const float* __restrict__ Mmax,
    float* __restrict__ cpart,
    const ushort_t* __restrict__ Wf, const ushort_t* __restrict__ Wb,
    const float* __restrict__ lp0,
    unsigned* __restrict__ amb, unsigned* __restrict__ bmb,
    unsigned* __restrict__ cmb, unsigned* __restrict__ rmb) {
  const float EPSF  = 1e-6f;
  const float EPS_S = 256.0f * 1e-6f;
  const int tid  = threadIdx.x;
  const int lane = tid & 63;
  const int wave = tid >> 6;
  const int xcd  = blockIdx.x & 7;
  const int slot = blockIdx.x >> 3;
  const int wg   = slot & 7;                 // 8 WGs per group
  const int grpg = (slot >> 3) * 8 + xcd;    // 0..31
  const bool isF = (grpg < 16);
  const int grp  = grpg & 15;
  const int b0   = grp * 16;
  const int jc0  = wg * 32;

  __shared__ float yred[2][4][2][64][4];     // parity-double-buffered
  __shared__ float rowUp[2][4][16];

  // persistent W fragments (bf16), per wave K-quarter, 2 n-tiles
  bf16x8 bfrag[8][2][2];
  {
    const ushort_t* Ws = isF ? Wf : Wb;
    #pragma unroll
    for (int a = 0; a < 8; ++a)
      #pragma unroll
      for (int kk = 0; kk < 2; ++kk)
        #pragma unroll
        for (int nt = 0; nt < 2; ++nt) {
          const int kc = wave * 2 + kk;
          const int fragid = (a * 8 + kc) * 16 + wg * 2 + nt;
          bfrag[a][kk][nt] = *reinterpret_cast<const bf16x8*>(Ws + (size_t)fragid * 512 + lane * 8);
        }
  }

  const int m_ = lane & 15;
  const int q_ = lane >> 4;
  const int frow = tid >> 4;
  const int fcol = tid & 15;
  const int lsrc = (frow >> 2) * 16 + fcol;
  const int rg_  = frow & 3;

  if (isF) {
    // ---- t = 0 init: alpha_hat(0) = exp(lx0 - M + logpi0)
    {
      float mm = Mmax[b0 + frow];
      float csum = 0.f;
      #pragma unroll
      for (int nt = 0; nt < 2; ++nt) {
        int j = jc0 + nt * 16 + fcol;
        float lx = __builtin_nontemporal_load(logp + (size_t)(b0 + frow) * SS + j);
        float v = __expf(lx - mm + lp0[j]);
        __builtin_nontemporal_store(v, out + (size_t)(b0 + frow) * SS + j);
        st_u32(&amb[((size_t)(0 * 16 + grp) * 16 + frow) * 256 + j], (unsigned)f2bf(v));
        csum += v;
      }
      #pragma unroll
      for (int o = 8; o >= 1; o >>= 1) csum += __shfl_down(csum, o, 16);
      if (fcol == 0) {
        __builtin_nontemporal_store(csum, &cpart[((size_t)grp * 16 + frow) * 8 + wg]);
        release_fence();   // amb data visible before flag
        st_u32(&cmb[((size_t)(0 * 16 + grp) * 16 + frow) * 8 + wg], (unsigned)f2bf(csum));
      }
    }

    for (int t = 1; t < TT; ++t) {
      const int par_r = (t - 1) & 1, par_w = t & 1;
      // ---- loop-top independent loads (overlap with poll)
      float wcur[4][8];
      {
        const float* ab = a_in + ((size_t)(t - 1) * BB + b0 + q_ * 4) * AA;
        #pragma unroll
        for (int r = 0; r < 4; ++r) {
          *reinterpret_cast<float4*>(&wcur[r][0]) = *reinterpret_cast<const float4*>(ab + r * AA);
          *reinterpret_cast<float4*>(&wcur[r][4]) = *reinterpret_cast<const float4*>(ab + r * AA + 4);
        }
      }
      float mmn = Mmax[(size_t)t * BB + b0 + frow];
      const float* lsp = logp + ((size_t)t * BB + b0 + frow) * SS + jc0;
      float lx0 = __builtin_nontemporal_load(lsp + fcol);
      float lx1 = __builtin_nontemporal_load(lsp + 16 + fcol);
      float ex0 = __expf(lx0 - mmn);
      float ex1 = __expf(lx1 - mmn);

      // ---- light poll: flags only (512B/iter/wave instead of ~4KB)
      const u64_t* pr = (const u64_t*)(amb + (((size_t)par_r * 16 + grp) * 16 + m_) * 256);
      const u64_t* p0 = pr + wave * 32 + q_ * 4;
      const u64_t* p1 = p0 + 16;
      const unsigned* pc  = cmb + (((size_t)par_r * 16 + grp) * 16 + (lane >> 3)) * 8 + (lane & 7);
      const unsigned* pc2 = pc + 64;
      const unsigned tg = (unsigned)(t - 1);
      unsigned clo, chi;
      while (true) {
        clo = ld_u32(pc); chi = ld_u32(pc2);
        bool ok = ((clo >> 16) == tg) & ((chi >> 16) == tg);
        if (__all(ok)) break;
      }
      __builtin_amdgcn_sched_barrier(0);   // keep data loads after flag pass
      // ---- bulk-read fragment data once
      u64_t d[8];
      #pragma unroll
      for (int k = 0; k < 4; ++k) { d[k] = ld_u64(p0 + k); d[4 + k] = ld_u64(p1 + k); }
      // ra (1/row-sum) via octet reduce + broadcast
      float slo = bf2f(clo), shi = bf2f(chi);
      slo += __shfl_xor(slo, 4, 8); slo += __shfl_xor(slo, 2, 8); slo += __shfl_xor(slo, 1, 8);
      shi += __shfl_xor(shi, 4, 8); shi += __shfl_xor(shi, 2, 8); shi += __shfl_xor(shi, 1, 8);
      float vlo = __shfl(slo, (m_ & 7) * 8);
      float vhi = __shfl(shi, (m_ & 7) * 8);
      float ra = 1.0f / ((m_ < 8) ? vlo : vhi);

      // ---- fragments + GEMM + a-mix combine
      float ys[2][4] = {{0.f,0.f,0.f,0.f},{0.f,0.f,0.f,0.f}};
      {
        bf16x8 af0, af1;
        #pragma unroll
        for (int e = 0; e < 8; ++e) {
          unsigned h0 = (e & 1) ? (unsigned)(d[e >> 1] >> 32) : (unsigned)d[e >> 1];
          unsigned h1 = (e & 1) ? (unsigned)(d[4 + (e >> 1)] >> 32) : (unsigned)d[4 + (e >> 1)];
          af0[e] = (__bf16)(bf2f(h0) * ra);
          af1[e] = (__bf16)(bf2f(h1) * ra);
        }
        #pragma unroll
        for (int a = 0; a < 8; ++a) {
          #pragma unroll
          for (int nt = 0; nt < 2; ++nt) {
            f32x4 c = {0.f, 0.f, 0.f, 0.f};
            c = __builtin_amdgcn_mfma_f32_16x16x32_bf16(af0, bfrag[a][0][nt], c, 0, 0, 0);
            c = __builtin_amdgcn_mfma_f32_16x16x32_bf16(af1, bfrag[a][1][nt], c, 0, 0, 0);
            #pragma unroll
            for (int r = 0; r < 4; ++r) ys[nt][r] += wcur[r][a] * c[r];
          }
        }
      }
      #pragma unroll
      for (int nt = 0; nt < 2; ++nt)
        *reinterpret_cast<float4*>(&yred[par_w][wave][nt][lane][0]) =
            make_float4(ys[nt][0], ys[nt][1], ys[nt][2], ys[nt][3]);
      __syncthreads();
      // ---- finalize + publish (data stores -> release -> flag)
      {
        float csum = 0.f;
        float* orow = out + ((size_t)t * BB + b0 + frow) * SS + jc0;
        unsigned* mrow = amb + (((size_t)par_w * 16 + grp) * 16 + frow) * 256 + jc0;
        float y0 = yred[par_w][0][0][lsrc][rg_] + yred[par_w][1][0][lsrc][rg_] +
                   yred[par_w][2][0][lsrc][rg_] + yred[par_w][3][0][lsrc][rg_];
        float bh0 = ex0 * (y0 + EPS_S);
        __builtin_nontemporal_store(bh0, orow + fcol);
        st_u32(mrow + fcol, ((unsigned)t << 16) | f2bf(bh0));
        csum += bh0;
        float y1 = yred[par_w][0][1][lsrc][rg_] + yred[par_w][1][1][lsrc][rg_] +
                   yred[par_w][2][1][lsrc][rg_] + yred[par_w][3][1][lsrc][rg_];
        float bh1 = ex1 * (y1 + EPS_S);
        __builtin_nontemporal_store(bh1, orow + 16 + fcol);
        st_u32(mrow + 16 + fcol, ((unsigned)t << 16) | f2bf(bh1));
        csum += bh1;
        #pragma unroll
        for (int o = 8; o >= 1; o >>= 1) csum += __shfl_down(csum, o, 16);
        if (fcol == 0) {
          __builtin_nontemporal_store(csum, &cpart[(((size_t)t * 16 + grp) * 16 + frow) * 8 + wg]);
          release_fence();   // this wave's amb stores visible before its flag
          st_u32(&cmb[(((size_t)par_w * 16 + grp) * 16 + frow) * 8 + wg],
                 ((unsigned)t << 16) | f2bf(csum));
        }
      }
    }
  } else {
    // ---- bwd init: beta_hat[T-1] = 1
    {
      const unsigned tg0 = (unsigned)(TT - 1);
      float* brow = beta + ((size_t)(TT - 1) * BB + b0 + frow) * SS + jc0;
      unsigned* mrow = bmb + (((size_t)((TT - 1) & 1) * 16 + grp) * 16 + frow) * 256 + jc0;
      __builtin_nontemporal_store(1.0f, brow + fcol);
      __builtin_nontemporal_store(1.0f, brow + 16 + fcol);
      st_u32(mrow + fcol, (tg0 << 16) | 0x3F80u);
      st_u32(mrow + 16 + fcol, (tg0 << 16) | 0x3F80u);
      if (fcol == 0) {
        release_fence();
        st_u32(&rmb[(((size_t)((TT - 1) & 1) * 16 + grp) * 16 + frow) * 8 + wg],
               (tg0 << 16) | f2bf(32.0f));
      }
    }

    for (int t = TT - 2; t >= 0; --t) {
      const int tr = t + 1;
      const int par_r = tr & 1, par_w = t & 1;
      // ---- loop-top independent loads
      float wcur[4][8];
      {
        const float* ab = a_in + ((size_t)t * BB + b0 + q_ * 4) * AA;
        #pragma unroll
        for (int r = 0; r < 4; ++r) {
          *reinterpret_cast<float4*>(&wcur[r][0]) = *reinterpret_cast<const float4*>(ab + r * AA);
          *reinterpret_cast<float4*>(&wcur[r][4]) = *reinterpret_cast<const float4*>(ab + r * AA + 4);
        }
      }
      float lp0v[8], lp1v[8];
      {
        // cacheable: each logp row is re-read by all 8 WGs of the group (L2 reuse)
        const float* lrow = logp + ((size_t)tr * BB + b0 + m_) * SS + wave * 64 + q_ * 8;
        *reinterpret_cast<float4*>(&lp0v[0]) = *reinterpret_cast<const float4*>(lrow);
        *reinterpret_cast<float4*>(&lp0v[4]) = *reinterpret_cast<const float4*>(lrow + 4);
        *reinterpret_cast<float4*>(&lp1v[0]) = *reinterpret_cast<const float4*>(lrow + 32);
        *reinterpret_cast<float4*>(&lp1v[4]) = *reinterpret_cast<const float4*>(lrow + 36);
      }
      float mm_ = Mmax[(size_t)tr * BB + b0 + m_];
      float mk  = mask[(size_t)tr * BB + b0 + frow];

      // ---- light poll: flags only
      const u64_t* pr = (const u64_t*)(bmb + (((size_t)par_r * 16 + grp) * 16 + m_) * 256);
      const u64_t* p0 = pr + wave * 32 + q_ * 4;
      const u64_t* p1 = p0 + 16;
      const unsigned* pc  = rmb + (((size_t)par_r * 16 + grp) * 16 + (lane >> 3)) * 8 + (lane & 7);
      const unsigned* pc2 = pc + 64;
      const unsigned tg = (unsigned)tr;
      unsigned clo, chi;
      while (true) {
        clo = ld_u32(pc); chi = ld_u32(pc2);
        bool ok = ((clo >> 16) == tg) & ((chi >> 16) == tg);
        if (__all(ok)) break;
      }
      __builtin_amdgcn_sched_barrier(0);
      u64_t d[8];
      #pragma unroll
      for (int k = 0; k < 4; ++k) { d[k] = ld_u64(p0 + k); d[4 + k] = ld_u64(p1 + k); }
      float slo = bf2f(clo), shi = bf2f(chi);
      slo += __shfl_xor(slo, 4, 8); slo += __shfl_xor(slo, 2, 8); slo += __shfl_xor(slo, 1, 8);
      shi += __shfl_xor(shi, 4, 8); shi += __shfl_xor(shi, 2, 8); shi += __shfl_xor(shi, 1, 8);
      float vlo = __shfl(slo, (m_ & 7) * 8);
      float vhi = __shfl(shi, (m_ & 7) * 8);
      float ri = 1.0f / ((m_ < 8) ? vlo : vhi);
      float vloF = __shfl(slo, (frow & 7) * 8);
      float vhiF = __shfl(shi, (frow & 7) * 8);
      float riF = 1.0f / ((frow < 8) ? vloF : vhiF);

      // ---- g = exp(lx-M)*beta_hat ; fragments + row partial
      float partial = 0.f;
      float ys[2][4] = {{0.f,0.f,0.f,0.f},{0.f,0.f,0.f,0.f}};
      {
        bf16x8 af0, af1;
        #pragma unroll
        for (int e = 0; e < 8; ++e) {
          unsigned h0 = (e & 1) ? (unsigned)(d[e >> 1] >> 32) : (unsigned)d[e >> 1];
          unsigned h1 = (e & 1) ? (unsigned)(d[4 + (e >> 1)] >> 32) : (unsigned)d[4 + (e >> 1)];
          float g0 = __expf(lp0v[e] - mm_) * bf2f(h0);
          float g1 = __expf(lp1v[e] - mm_) * bf2f(h1);
          partial += g0 + g1;
          af0[e] = (__bf16)(g0 * ri);
          af1[e] = (__bf16)(g1 * ri);
        }
        #pragma unroll
        for (int a = 0; a < 8; ++a) {
          #pragma unroll
          for (int nt = 0; nt < 2; ++nt) {
            f32x4 c = {0.f, 0.f, 0.f, 0.f};
            c = __builtin_amdgcn_mfma_f32_16x16x32_bf16(af0, bfrag[a][0][nt], c, 0, 0, 0);
            c = __builtin_amdgcn_mfma_f32_16x16x32_bf16(af1, bfrag[a][1][nt], c, 0, 0, 0);
            #pragma unroll
            for (int r = 0; r < 4; ++r) ys[nt][r] += wcur[r][a] * c[r];
          }
        }
      }
      partial += __shfl_xor(partial, 16);
      partial += __shfl_xor(partial, 32);
      if (q_ == 0) rowUp[par_w][wave][m_] = partial;
      #pragma unroll
      for (int nt = 0; nt < 2; ++nt)
        *reinterpret_cast<float4*>(&yred[par_w][wave][nt][lane][0]) =
            make_float4(ys[nt][0], ys[nt][1], ys[nt][2], ys[nt][3]);
      __syncthreads();
      // ---- finalize + publish (data stores -> release -> flag)
      {
        float rowU = rowUp[par_w][0][frow] + rowUp[par_w][1][frow] +
                     rowUp[par_w][2][frow] + rowUp[par_w][3][frow];
        float eg = EPSF * riF * rowU;
        bool mk1 = (mk == 1.0f);
        float rsum = 0.f;
        float* brow = beta + ((size_t)t * BB + b0 + frow) * SS + jc0;
        unsigned* mrow = bmb + (((size_t)par_w * 16 + grp) * 16 + frow) * 256 + jc0;
        #pragma unroll
        for (int nt = 0; nt < 2; ++nt) {
          float y = yred[par_w][0][nt][lsrc][rg_] + yred[par_w][1][nt][lsrc][rg_] +
                    yred[par_w][2][nt][lsrc][rg_] + yred[par_w][3][nt][lsrc][rg_];
          float val = mk1 ? (y + eg) : 1.0f;
          __builtin_nontemporal_store(val, brow + nt * 16 + fcol);
          st_u32(mrow + nt * 16 + fcol, ((unsigned)t << 16) | f2bf(val));
          rsum += val;
        }
        #pragma unroll
        for (int o = 8; o >= 1; o >>= 1) rsum += __shfl_down(rsum, o, 16);
        if (fcol == 0) {
          release_fence();
          st_u32(&rmb[(((size_t)par_w * 16 + grp) * 16 + frow) * 8 + wg],
                 ((unsigned)t << 16) | f2bf(rsum));
        }
      }
    }
  }
}

// ---------------- epilogue: q_z = softmax(log(alpha_hat + c*EPS) + log(beta_hat)) ----------------
__global__ __launch_bounds__(256) void k_qz(float* __restrict__ out,
    const float* __restrict__ beta, const float* __restrict__ cpart) {
  const float EPSF = 1e-6f;
  int tid = threadIdx.x;
  size_t row = (size_t)blockIdx.x * 8 + (tid >> 5);
  int l = tid & 31;
  int tt = (int)(row >> 8);
  int b  = (int)(row & 255);
  int grp = b >> 4, r = b & 15;
  float pv = 0.f;
  if (l < 8) pv = cpart[(((size_t)tt * 16 + grp) * 16 + r) * 8 + l];
  pv += __shfl_down(pv, 4, 8); pv += __shfl_down(pv, 2, 8); pv += __shfl_down(pv, 1, 8);
  float ce = __shfl(pv, 0, 32) * EPSF;
  float* po = out + row * SS + l * 8;
  const float* pb = beta + row * SS + l * 8;
  f32x4 v0 = __builtin_nontemporal_load(reinterpret_cast<const f32x4*>(po));
  f32x4 v1 = __builtin_nontemporal_load(reinterpret_cast<const f32x4*>(po + 4));
  f32x4 b0 = __builtin_nontemporal_load(reinterpret_cast<const f32x4*>(pb));
  f32x4 b1 = __builtin_nontemporal_load(reinterpret_cast<const f32x4*>(pb + 4));
  float z[8];
  z[0] = __logf(v0[0] + ce) + __logf(b0[0]);
  z[1] = __logf(v0[1] + ce) + __logf(b0[1]);
  z[2] = __logf(v0[2] + ce) + __logf(b0[2]);
  z[3] = __logf(v0[3] + ce) + __logf(b0[3]);
  z[4] = __logf(v1[0] + ce) + __logf(b1[0]);
  z[5] = __logf(v1[1] + ce) + __logf(b1[1]);
  z[6] = __logf(v1[2] + ce) + __logf(b1[2]);
  z[7] = __logf(v1[3] + ce) + __logf(b1[3]);
  float m = z[0];
  #pragma unroll
  for (int k = 1; k < 8; ++k) m = fmaxf(m, z[k]);
  #pragma unroll
  for (int o = 16; o >= 1; o >>= 1) m = fmaxf(m, __shfl_xor(m, o, 32));
  float e[8]; float s = 0.f;
  #pragma unroll
  for (int k = 0; k < 8; ++k) { e[k] = __expf(z[k] - m); s += e[k]; }
  #pragma unroll
  for (int o = 16; o >= 1; o >>= 1) s += __shfl_xor(s, o, 32);
  float inv = 1.0f / s;
  f32x4 r0 = { e[0]*inv, e[1]*inv, e[2]*inv, e[3]*inv };
  f32x4 r1 = { e[4]*inv, e[5]*inv, e[6]*inv, e[7]*inv };
  __builtin_nontemporal_store(r0, reinterpret_cast<f32x4*>(po));
  __builtin_nontemporal_store(r1, reinterpret_cast<f32x4*>(po + 4));
}

extern "C" void kernel_launch(void* const* d_in, const int* in_sizes, int n_in,
                              void* d_out, int out_size, void* d_ws, size_t ws_size,
                              hipStream_t stream) {
  (void)in_sizes; (void)n_in; (void)out_size;
  const float* x   = (const float*)d_in[0];
  const float* a   = (const float*)d_in[1];
  const float* msk = (const float*)d_in[2];
  const float* mu  = (const float*)d_in[3];
  const float* lv  = (const float*)d_in[4];
  const float* wl  = (const float*)d_in[5];
  const float* s0  = (const float*)d_in[6];
  float* out = (float*)d_out;

  char* ws = (char*)d_ws;
  float* logp  = (float*)ws;  ws += (size_t)TT * BB * SS * 4;
  float* beta  = (float*)ws;  ws += (size_t)TT * BB * SS * 4;
  float* Mmax  = (float*)ws;  ws += (size_t)TT * BB * 4;
  float* cpart = (float*)ws;  ws += (size_t)TT * BB * 8 * 4;   // [T][16][16][8]
  ushort_t* Wf = (ushort_t*)ws; ws += (size_t)AA * SS * SS * 2;
  ushort_t* Wb = (ushort_t*)ws; ws += (size_t)AA * SS * SS * 2;
  float* A1 = (float*)ws;    ws += (size_t)SS * DD * 4;
  float* A2 = (float*)ws;    ws += (size_t)SS * DD * 4;
  float* Cs = (float*)ws;    ws += 1024;
  float* lp0 = (float*)ws;   ws += 1024;
  unsigned* amb = (unsigned*)ws; ws += (size_t)2 * 16 * 16 * 256 * 4;  // 512 KB
  unsigned* bmb = (unsigned*)ws; ws += (size_t)2 * 16 * 16 * 256 * 4;  // 512 KB
  unsigned* cmb = (unsigned*)ws; ws += (size_t)2 * 16 * 16 * 8 * 4;    // 16 KB
  unsigned* rmb = (unsigned*)ws; ws += (size_t)2 * 16 * 16 * 8 * 4;    // 16 KB
  if (ws_size < (size_t)(ws - (char*)d_ws)) return;

  // invalidate flag tags only (0xFFFF != any step tag); amb/bmb data is never
  // read before its flag is published, so it needs no init.
  hipMemsetAsync(cmb, 0xFF, (size_t)(2 * 16 * 16 * 8 * 4) * 2, stream);

  k_params<<<SS, DD, 0, stream>>>(mu, lv, A1, A2, Cs);
  k_pi0<<<1, SS, 0, stream>>>(s0, lp0);
  k_trans<<<256, 256, 0, stream>>>(wl, Wf, Wb);
  k_logp<<<TT * BB / 32, 256, 0, stream>>>(x, A1, A2, Cs, logp, Mmax);
  k_recur<<<256, 256, 0, stream>>>(a, msk, out, beta, logp, Mmax, cpart, Wf, Wb, lp0,
                                   amb, bmb, cmb, rmb);
  k_qz<<<TT * BB / 8, 256, 0, stream>>>(out, beta, cpart);
}

// Round 2
// 2076.343 us; speedup vs baseline: 1.6520x; 1.6520x over previous
//
#include <hip/hip_runtime.h>
#include <hip/hip_bf16.h>

#define TT 512
#define BB 256
#define SS 256
#define AA 8
#define DD 64

typedef unsigned short ushort_t;
typedef unsigned long long u64_t;
typedef __bf16 bf16x8 __attribute__((ext_vector_type(8)));
typedef float  f32x4  __attribute__((ext_vector_type(4)));
typedef unsigned int u32x4v __attribute__((ext_vector_type(4)));
typedef unsigned int u32x2v __attribute__((ext_vector_type(2)));

__device__ __forceinline__ ushort_t f2bf(float x) {
  union { float f; unsigned u; } v; v.f = x;
  unsigned r = (v.u + 0x7FFFu + ((v.u >> 16) & 1u)) >> 16;
  return (ushort_t)r;
}
__device__ __forceinline__ float bf2f(unsigned h) {
  return __uint_as_float((h & 0xFFFFu) << 16);
}
__device__ __forceinline__ void st_u32(unsigned* p, unsigned v) {
  __hip_atomic_store(p, v, __ATOMIC_RELAXED, __HIP_MEMORY_SCOPE_AGENT);
}

// One poll iteration: 64B of mailbox data + both flag words in 5 wide coherent
// loads (sc0 sc1 = bypass L1+L2, served at device coherence point — same
// semantics as relaxed agent atomic loads, but 4 transactions/lane instead of 10).
__device__ __forceinline__ void poll_once(const u64_t* p0, const u64_t* p1,
                                          const u64_t* pcf,
                                          u64_t d[8], unsigned& clo, unsigned& chi) {
  u32x4v a0, a1, a2, a3; u32x2v cf;
  asm volatile(
      "global_load_dwordx4 %0, %5, off sc0 sc1\n\t"
      "global_load_dwordx4 %1, %6, off sc0 sc1\n\t"
      "global_load_dwordx4 %2, %7, off sc0 sc1\n\t"
      "global_load_dwordx4 %3, %8, off sc0 sc1\n\t"
      "global_load_dwordx2 %4, %9, off sc0 sc1\n\t"
      "s_waitcnt vmcnt(0)"
      : "=&v"(a0), "=&v"(a1), "=&v"(a2), "=&v"(a3), "=&v"(cf)
      : "v"(p0), "v"(p0 + 2), "v"(p1), "v"(p1 + 2), "v"(pcf)
      : "memory");
  d[0] = (u64_t)a0[0] | ((u64_t)a0[1] << 32);
  d[1] = (u64_t)a0[2] | ((u64_t)a0[3] << 32);
  d[2] = (u64_t)a1[0] | ((u64_t)a1[1] << 32);
  d[3] = (u64_t)a1[2] | ((u64_t)a1[3] << 32);
  d[4] = (u64_t)a2[0] | ((u64_t)a2[1] << 32);
  d[5] = (u64_t)a2[2] | ((u64_t)a2[3] << 32);
  d[6] = (u64_t)a3[0] | ((u64_t)a3[1] << 32);
  d[7] = (u64_t)a3[2] | ((u64_t)a3[3] << 32);
  clo = cf[0]; chi = cf[1];
}

// ---------------- prologue: per-state Gaussian params ----------------
__global__ __launch_bounds__(64) void k_params(const float* __restrict__ mu,
                                               const float* __restrict__ lv,
                                               float* __restrict__ A1, float* __restrict__ A2,
                                               float* __restrict__ Cs) {
  const float LOG2PI = 1.8378770664093453f;
  int s = blockIdx.x, d = threadIdx.x;
  float l = lv[s * DD + d], m_ = mu[s * DD + d];
  float inv = __expf(-l);
  A1[s * DD + d] = inv;
  A2[s * DD + d] = m_ * inv;
  float part = m_ * m_ * inv + l;
  #pragma unroll
  for (int o = 32; o >= 1; o >>= 1) part += __shfl_down(part, o);
  if (d == 0) Cs[s] = part + (float)DD * LOG2PI;
}

// ---------------- prologue: log_softmax of s0_logits ----------------
__global__ __launch_bounds__(256) void k_pi0(const float* __restrict__ s0, float* __restrict__ lp0) {
  __shared__ float red[4];
  int tid = threadIdx.x, ln = tid & 63, wv = tid >> 6;
  float v = s0[tid];
  float m = v;
  #pragma unroll
  for (int o = 32; o >= 1; o >>= 1) m = fmaxf(m, __shfl_xor(m, o));
  if (ln == 0) red[wv] = m;
  __syncthreads();
  m = fmaxf(fmaxf(red[0], red[1]), fmaxf(red[2], red[3]));
  __syncthreads();
  float e = __expf(v - m);
  float s = e;
  #pragma unroll
  for (int o = 32; o >= 1; o >>= 1) s += __shfl_xor(s, o);
  if (ln == 0) red[wv] = s;
  __syncthreads();
  s = red[0] + red[1] + red[2] + red[3];
  lp0[tid] = v - m - __logf(s);
}

// ---------------- prologue: softmax(w_logits) -> bf16 MFMA B-fragment layouts ----------------
__global__ __launch_bounds__(256) void k_trans(const float* __restrict__ wl,
                                               ushort_t* __restrict__ Wf, ushort_t* __restrict__ Wb) {
  int tid = threadIdx.x;
  int rl = tid >> 5, l = tid & 31;
  int row = blockIdx.x * 8 + rl;      // row = a*256 + i
  int a = row >> 8, i = row & 255;
  const float* src = wl + (size_t)row * 256 + l * 8;
  float v[8];
  *reinterpret_cast<float4*>(&v[0]) = *reinterpret_cast<const float4*>(src);
  *reinterpret_cast<float4*>(&v[4]) = *reinterpret_cast<const float4*>(src + 4);
  float m = v[0];
  #pragma unroll
  for (int k = 1; k < 8; ++k) m = fmaxf(m, v[k]);
  #pragma unroll
  for (int o = 16; o >= 1; o >>= 1) m = fmaxf(m, __shfl_xor(m, o, 32));
  float s = 0.f;
  #pragma unroll
  for (int k = 0; k < 8; ++k) { v[k] = __expf(v[k] - m); s += v[k]; }
  #pragma unroll
  for (int o = 16; o >= 1; o >>= 1) s += __shfl_xor(s, o, 32);
  float inv = 1.0f / s;
  #pragma unroll
  for (int k = 0; k < 8; ++k) {
    int j = l * 8 + k;
    ushort_t h = f2bf(v[k] * inv);
    size_t fi = (size_t)((a * 8 + (i >> 5)) * 16 + (j >> 4));
    Wf[fi * 512 + (((i >> 3) & 3) * 16 + (j & 15)) * 8 + (i & 7)] = h;
    size_t bi = (size_t)((a * 8 + (j >> 5)) * 16 + (i >> 4));
    Wb[bi * 512 + (((j >> 3) & 3) * 16 + (i & 15)) * 8 + (j & 7)] = h;
  }
}

// ---------------- logp_x [T,B,S] in fp32 + per-row max ----------------
__global__ __launch_bounds__(256) void k_logp(const float* __restrict__ x,
    const float* __restrict__ A1, const float* __restrict__ A2,
    const float* __restrict__ Cs, float* __restrict__ logp, float* __restrict__ Mmax) {
  __shared__ float sA1[64][64];
  __shared__ float sA2[64][64];
  int tid = threadIdx.x;
  int row = tid >> 3, dg = tid & 7;
  size_t row0 = (size_t)blockIdx.x * 32;
  const float* xp = x + (row0 + row) * DD + dg * 8;
  float xv[8];
  *reinterpret_cast<float4*>(&xv[0]) = *reinterpret_cast<const float4*>(xp);
  *reinterpret_cast<float4*>(&xv[4]) = *reinterpret_cast<const float4*>(xp + 4);
  float m = -3.0e38f;
  float* orow = logp + (row0 + row) * SS;
  for (int st = 0; st < 4; ++st) {
    __syncthreads();
    #pragma unroll
    for (int k = 0; k < 4; ++k) {
      int flat = k * 1024 + tid * 4;
      int sr = flat >> 6, sc = flat & 63;
      *reinterpret_cast<float4*>(&sA1[sr][sc]) = *reinterpret_cast<const float4*>(&A1[(size_t)(st * 64 + sr) * 64 + sc]);
      *reinterpret_cast<float4*>(&sA2[sr][sc]) = *reinterpret_cast<const float4*>(&A2[(size_t)(st * 64 + sr) * 64 + sc]);
    }
    __syncthreads();
    for (int s = 0; s < 64; ++s) {
      float acc = 0.f;
      #pragma unroll
      for (int j = 0; j < 8; ++j) {
        float t1 = __builtin_fmaf(sA1[s][dg * 8 + j], xv[j], -2.0f * sA2[s][dg * 8 + j]);
        acc = __builtin_fmaf(t1, xv[j], acc);
      }
      acc += __shfl_xor(acc, 1, 8);
      acc += __shfl_xor(acc, 2, 8);
      acc += __shfl_xor(acc, 4, 8);
      float lp = -0.5f * (acc + Cs[st * 64 + s]);
      m = fmaxf(m, lp);
      if (((s ^ dg) & 7) == 0) orow[st * 64 + s] = lp;
    }
  }
  if (dg == 0) Mmax[row0 + row] = m;
}

// ---------------- recursion: barrier-free tagged-mailbox pipeline ----------------
// amb/bmb: [2 parity][16 grp][16 row][256 col] u32 = (tag16 | bf16 payload)
// cmb/rmb: [2 parity][16 grp][8 pair][8 wg][2 half] u32 = (tag16 | bf16 row-partial-sum)
//          row r -> pair=r&7, half=r>>3; consumer lane ln reads pair=ln>>3, wg=ln&7
//          as ONE u64 (rows ln>>3 and (ln>>3)+8 adjacent).
// Data-polling: tags embedded per word; detection == data arrival; no fences.
__global__ __launch_bounds__(256, 1) void k_recur(
    const float* __restrict__ a_in, const float* __restrict__ mask,
    float* __restrict__ out, float* __restrict__ beta,
    const float* __restrict__ logp, const float* __restrict__ Mmax,
    float* __restrict__ cpart,
    const ushort_t* __restrict__ Wf, const ushort_t* __restrict__ Wb,
    const float* __restrict__ lp0,
    unsigned* __restrict__ amb, unsigned* __restrict__ bmb,
    unsigned* __restrict__ cmb, unsigned* __restrict__ rmb) {
  const float EPSF  = 1e-6f;
  const float EPS_S = 256.0f * 1e-6f;
  const int tid  = threadIdx.x;
  const int lane = tid & 63;
  const int wave = tid >> 6;
  const int xcd  = blockIdx.x & 7;
  const int slot = blockIdx.x >> 3;
  const int wg   = slot & 7;                 // 8 WGs per group
  const int grpg = (slot >> 3) * 8 + xcd;    // 0..31
  const bool isF = (grpg < 16);
  const int grp  = grpg & 15;
  const int b0   = grp * 16;
  const int jc0  = wg * 32;

  __shared__ float yred[2][4][2][64][4];     // parity-double-buffered
  __shared__ float rowUp[2][4][16];

  // persistent W fragments (bf16), per wave K-quarter, 2 n-tiles
  bf16x8 bfrag[8][2][2];
  {
    const ushort_t* Ws = isF ? Wf : Wb;
    #pragma unroll
    for (int a = 0; a < 8; ++a)
      #pragma unroll
      for (int kk = 0; kk < 2; ++kk)
        #pragma unroll
        for (int nt = 0; nt < 2; ++nt) {
          const int kc = wave * 2 + kk;
          const int fragid = (a * 8 + kc) * 16 + wg * 2 + nt;
          bfrag[a][kk][nt] = *reinterpret_cast<const bf16x8*>(Ws + (size_t)fragid * 512 + lane * 8);
        }
  }

  const int m_ = lane & 15;
  const int q_ = lane >> 4;
  const int frow = tid >> 4;
  const int fcol = tid & 15;
  const int lsrc = (frow >> 2) * 16 + fcol;
  const int rg_  = frow & 3;
  const u64_t TAGMASK = 0xFFFF0000FFFF0000ULL;
  // flag word index for publisher (this wave's row `frow`, slot `wg`)
  const size_t fpub = (size_t)(frow & 7) * 16 + wg * 2 + (frow >> 3);   // within [grp] block of 128 words

  if (isF) {
    // ---- t = 0 init: alpha_hat(0) = exp(lx0 - M + logpi0)
    {
      float mm = Mmax[b0 + frow];
      float csum = 0.f;
      #pragma unroll
      for (int nt = 0; nt < 2; ++nt) {
        int j = jc0 + nt * 16 + fcol;
        float lx = logp[(size_t)(b0 + frow) * SS + j];
        float v = __expf(lx - mm + lp0[j]);
        st_u32(&amb[((size_t)(0 * 16 + grp) * 16 + frow) * 256 + j], (unsigned)f2bf(v));
        out[(size_t)(b0 + frow) * SS + j] = v;
        csum += v;
      }
      #pragma unroll
      for (int o = 8; o >= 1; o >>= 1) csum += __shfl_down(csum, o, 16);
      if (fcol == 0) {
        st_u32(&cmb[((size_t)(0 * 16 + grp)) * 128 + fpub], (unsigned)f2bf(csum));
        cpart[((size_t)grp * 16 + frow) * 8 + wg] = csum;
      }
    }

    for (int t = 1; t < TT; ++t) {
      const int par_r = (t - 1) & 1, par_w = t & 1;
      // ---- loop-top independent loads (overlap with poll)
      float wcur[4][8];
      {
        const float* ab = a_in + ((size_t)(t - 1) * BB + b0 + q_ * 4) * AA;
        #pragma unroll
        for (int r = 0; r < 4; ++r) {
          *reinterpret_cast<float4*>(&wcur[r][0]) = *reinterpret_cast<const float4*>(ab + r * AA);
          *reinterpret_cast<float4*>(&wcur[r][4]) = *reinterpret_cast<const float4*>(ab + r * AA + 4);
        }
      }
      float mmn = Mmax[(size_t)t * BB + b0 + frow];
      const float* lsp = logp + ((size_t)t * BB + b0 + frow) * SS + jc0;
      float ex0 = __expf(lsp[fcol] - mmn);
      float ex1 = __expf(lsp[16 + fcol] - mmn);

      // ---- poll: 64B data + flag-pair per lane, 5 wide loads per iteration
      const u64_t* pr = (const u64_t*)(amb + (((size_t)par_r * 16 + grp) * 16 + m_) * 256);
      const u64_t* p0 = pr + wave * 32 + q_ * 4;
      const u64_t* p1 = p0 + 16;
      const u64_t* pcf = (const u64_t*)cmb + ((size_t)par_r * 16 + grp) * 64 + (lane >> 3) * 8 + (lane & 7);
      const unsigned tg = (unsigned)(t - 1);
      const u64_t pat = ((u64_t)tg << 48) | ((u64_t)tg << 16);
      u64_t d[8]; unsigned clo, chi;
      while (true) {
        poll_once(p0, p1, pcf, d, clo, chi);
        bool ok = ((clo >> 16) == tg) & ((chi >> 16) == tg);
        #pragma unroll
        for (int k = 0; k < 8; ++k) ok &= ((d[k] & TAGMASK) == pat);
        if (__all(ok)) break;
      }
      // ra (1/row-sum) via octet reduce + broadcast
      float slo = bf2f(clo), shi = bf2f(chi);
      slo += __shfl_xor(slo, 4, 8); slo += __shfl_xor(slo, 2, 8); slo += __shfl_xor(slo, 1, 8);
      shi += __shfl_xor(shi, 4, 8); shi += __shfl_xor(shi, 2, 8); shi += __shfl_xor(shi, 1, 8);
      float vlo = __shfl(slo, (m_ & 7) * 8);
      float vhi = __shfl(shi, (m_ & 7) * 8);
      float ra = 1.0f / ((m_ < 8) ? vlo : vhi);

      // ---- fragments + GEMM + a-mix combine
      float ys[2][4] = {{0.f,0.f,0.f,0.f},{0.f,0.f,0.f,0.f}};
      {
        bf16x8 af0, af1;
        #pragma unroll
        for (int e = 0; e < 8; ++e) {
          unsigned h0 = (e & 1) ? (unsigned)(d[e >> 1] >> 32) : (unsigned)d[e >> 1];
          unsigned h1 = (e & 1) ? (unsigned)(d[4 + (e >> 1)] >> 32) : (unsigned)d[4 + (e >> 1)];
          af0[e] = (__bf16)(bf2f(h0) * ra);
          af1[e] = (__bf16)(bf2f(h1) * ra);
        }
        #pragma unroll
        for (int a = 0; a < 8; ++a) {
          #pragma unroll
          for (int nt = 0; nt < 2; ++nt) {
            f32x4 c = {0.f, 0.f, 0.f, 0.f};
            c = __builtin_amdgcn_mfma_f32_16x16x32_bf16(af0, bfrag[a][0][nt], c, 0, 0, 0);
            c = __builtin_amdgcn_mfma_f32_16x16x32_bf16(af1, bfrag[a][1][nt], c, 0, 0, 0);
            #pragma unroll
            for (int r = 0; r < 4; ++r) ys[nt][r] += wcur[r][a] * c[r];
          }
        }
      }
      #pragma unroll
      for (int nt = 0; nt < 2; ++nt)
        *reinterpret_cast<float4*>(&yred[par_w][wave][nt][lane][0]) =
            make_float4(ys[nt][0], ys[nt][1], ys[nt][2], ys[nt][3]);
      __syncthreads();
      // ---- finalize: mailbox/flag publishes FIRST, background stores after
      {
        float* orow = out + ((size_t)t * BB + b0 + frow) * SS + jc0;
        unsigned* mrow = amb + (((size_t)par_w * 16 + grp) * 16 + frow) * 256 + jc0;
        float y0 = yred[par_w][0][0][lsrc][rg_] + yred[par_w][1][0][lsrc][rg_] +
                   yred[par_w][2][0][lsrc][rg_] + yred[par_w][3][0][lsrc][rg_];
        float y1 = yred[par_w][0][1][lsrc][rg_] + yred[par_w][1][1][lsrc][rg_] +
                   yred[par_w][2][1][lsrc][rg_] + yred[par_w][3][1][lsrc][rg_];
        float bh0 = ex0 * (y0 + EPS_S);
        float bh1 = ex1 * (y1 + EPS_S);
        st_u32(mrow + fcol, ((unsigned)t << 16) | f2bf(bh0));
        st_u32(mrow + 16 + fcol, ((unsigned)t << 16) | f2bf(bh1));
        float csum = bh0 + bh1;
        #pragma unroll
        for (int o = 8; o >= 1; o >>= 1) csum += __shfl_down(csum, o, 16);
        if (fcol == 0)
          st_u32(&cmb[((size_t)par_w * 16 + grp) * 128 + fpub],
                 ((unsigned)t << 16) | f2bf(csum));
        // background
        orow[fcol] = bh0;
        orow[16 + fcol] = bh1;
        if (fcol == 0) {
          float cs = __shfl(csum, (tid >> 4) * 16, 64);  // csum already at fcol==0 lane
          cpart[(((size_t)t * 16 + grp) * 16 + frow) * 8 + wg] = cs;
        }
      }
    }
  } else {
    // ---- bwd init: beta_hat[T-1] = 1
    {
      const unsigned tg0 = (unsigned)(TT - 1);
      float* brow = beta + ((size_t)(TT - 1) * BB + b0 + frow) * SS + jc0;
      unsigned* mrow = bmb + (((size_t)((TT - 1) & 1) * 16 + grp) * 16 + frow) * 256 + jc0;
      st_u32(mrow + fcol, (tg0 << 16) | 0x3F80u);
      st_u32(mrow + 16 + fcol, (tg0 << 16) | 0x3F80u);
      brow[fcol] = 1.0f; brow[16 + fcol] = 1.0f;
      if (fcol == 0)
        st_u32(&rmb[((size_t)((TT - 1) & 1) * 16 + grp) * 128 + fpub],
               (tg0 << 16) | f2bf(32.0f));
    }

    for (int t = TT - 2; t >= 0; --t) {
      const int tr = t + 1;
      const int par_r = tr & 1, par_w = t & 1;
      // ---- loop-top independent loads
      float wcur[4][8];
      {
        const float* ab = a_in + ((size_t)t * BB + b0 + q_ * 4) * AA;
        #pragma unroll
        for (int r = 0; r < 4; ++r) {
          *reinterpret_cast<float4*>(&wcur[r][0]) = *reinterpret_cast<const float4*>(ab + r * AA);
          *reinterpret_cast<float4*>(&wcur[r][4]) = *reinterpret_cast<const float4*>(ab + r * AA + 4);
        }
      }
      float lp0v[8], lp1v[8];
      {
        const float* lrow = logp + ((size_t)tr * BB + b0 + m_) * SS + wave * 64 + q_ * 8;
        *reinterpret_cast<float4*>(&lp0v[0]) = *reinterpret_cast<const float4*>(lrow);
        *reinterpret_cast<float4*>(&lp0v[4]) = *reinterpret_cast<const float4*>(lrow + 4);
        *reinterpret_cast<float4*>(&lp1v[0]) = *reinterpret_cast<const float4*>(lrow + 32);
        *reinterpret_cast<float4*>(&lp1v[4]) = *reinterpret_cast<const float4*>(lrow + 36);
      }
      float mm_ = Mmax[(size_t)tr * BB + b0 + m_];
      float mk  = mask[(size_t)tr * BB + b0 + frow];

      // ---- poll
      const u64_t* pr = (const u64_t*)(bmb + (((size_t)par_r * 16 + grp) * 16 + m_) * 256);
      const u64_t* p0 = pr + wave * 32 + q_ * 4;
      const u64_t* p1 = p0 + 16;
      const u64_t* pcf = (const u64_t*)rmb + ((size_t)par_r * 16 + grp) * 64 + (lane >> 3) * 8 + (lane & 7);
      const unsigned tg = (unsigned)tr;
      const u64_t pat = ((u64_t)tg << 48) | ((u64_t)tg << 16);
      u64_t d[8]; unsigned clo, chi;
      while (true) {
        poll_once(p0, p1, pcf, d, clo, chi);
        bool ok = ((clo >> 16) == tg) & ((chi >> 16) == tg);
        #pragma unroll
        for (int k = 0; k < 8; ++k) ok &= ((d[k] & TAGMASK) == pat);
        if (__all(ok)) break;
      }
      float slo = bf2f(clo), shi = bf2f(chi);
      slo += __shfl_xor(slo, 4, 8); slo += __shfl_xor(slo, 2, 8); slo += __shfl_xor(slo, 1, 8);
      shi += __shfl_xor(shi, 4, 8); shi += __shfl_xor(shi, 2, 8); shi += __shfl_xor(shi, 1, 8);
      float vlo = __shfl(slo, (m_ & 7) * 8);
      float vhi = __shfl(shi, (m_ & 7) * 8);
      float ri = 1.0f / ((m_ < 8) ? vlo : vhi);
      float vloF = __shfl(slo, (frow & 7) * 8);
      float vhiF = __shfl(shi, (frow & 7) * 8);
      float riF = 1.0f / ((frow < 8) ? vloF : vhiF);

      // ---- g = exp(lx-M)*beta_hat ; fragments + row partial
      float partial = 0.f;
      float ys[2][4] = {{0.f,0.f,0.f,0.f},{0.f,0.f,0.f,0.f}};
      {
        bf16x8 af0, af1;
        #pragma unroll
        for (int e = 0; e < 8; ++e) {
          unsigned h0 = (e & 1) ? (unsigned)(d[e >> 1] >> 32) : (unsigned)d[e >> 1];
          unsigned h1 = (e & 1) ? (unsigned)(d[4 + (e >> 1)] >> 32) : (unsigned)d[4 + (e >> 1)];
          float g0 = __expf(lp0v[e] - mm_) * bf2f(h0);
          float g1 = __expf(lp1v[e] - mm_) * bf2f(h1);
          partial += g0 + g1;
          af0[e] = (__bf16)(g0 * ri);
          af1[e] = (__bf16)(g1 * ri);
        }
        #pragma unroll
        for (int a = 0; a < 8; ++a) {
          #pragma unroll
          for (int nt = 0; nt < 2; ++nt) {
            f32x4 c = {0.f, 0.f, 0.f, 0.f};
            c = __builtin_amdgcn_mfma_f32_16x16x32_bf16(af0, bfrag[a][0][nt], c, 0, 0, 0);
            c = __builtin_amdgcn_mfma_f32_16x16x32_bf16(af1, bfrag[a][1][nt], c, 0, 0, 0);
            #pragma unroll
            for (int r = 0; r < 4; ++r) ys[nt][r] += wcur[r][a] * c[r];
          }
        }
      }
      partial += __shfl_xor(partial, 16);
      partial += __shfl_xor(partial, 32);
      if (q_ == 0) rowUp[par_w][wave][m_] = partial;
      #pragma unroll
      for (int nt = 0; nt < 2; ++nt)
        *reinterpret_cast<float4*>(&yred[par_w][wave][nt][lane][0]) =
            make_float4(ys[nt][0], ys[nt][1], ys[nt][2], ys[nt][3]);
      __syncthreads();
      // ---- finalize: mailbox/flag publishes FIRST, background stores after
      {
        float rowU = rowUp[par_w][0][frow] + rowUp[par_w][1][frow] +
                     rowUp[par_w][2][frow] + rowUp[par_w][3][frow];
        float eg = EPSF * riF * rowU;
        bool mk1 = (mk == 1.0f);
        float* brow = beta + ((size_t)t * BB + b0 + frow) * SS + jc0;
        unsigned* mrow = bmb + (((size_t)par_w * 16 + grp) * 16 + frow) * 256 + jc0;
        float y0 = yred[par_w][0][0][lsrc][rg_] + yred[par_w][1][0][lsrc][rg_] +
                   yred[par_w][2][0][lsrc][rg_] + yred[par_w][3][0][lsrc][rg_];
        float y1 = yred[par_w][0][1][lsrc][rg_] + yred[par_w][1][1][lsrc][rg_] +
                   yred[par_w][2][1][lsrc][rg_] + yred[par_w][3][1][lsrc][rg_];
        float v0 = mk1 ? (y0 + eg) : 1.0f;
        float v1 = mk1 ? (y1 + eg) : 1.0f;
        st_u32(mrow + fcol, ((unsigned)t << 16) | f2bf(v0));
        st_u32(mrow + 16 + fcol, ((unsigned)t << 16) | f2bf(v1));
        float rsum = v0 + v1;
        #pragma unroll
        for (int o = 8; o >= 1; o >>= 1) rsum += __shfl_down(rsum, o, 16);
        if (fcol == 0)
          st_u32(&rmb[((size_t)par_w * 16 + grp) * 128 + fpub],
                 ((unsigned)t << 16) | f2bf(rsum));
        // background
        brow[fcol] = v0;
        brow[16 + fcol] = v1;
      }
    }
  }
}

// ---------------- epilogue: q_z = softmax(log(alpha_hat + c*EPS) + log(beta_hat)) ----------------
__global__ __launch_bounds__(256) void k_qz(float* __restrict__ out,
    const float* __restrict__ beta, const float* __restrict__ cpart) {
  const float EPSF = 1e-6f;
  int tid = threadIdx.x;
  size_t row = (size_t)blockIdx.x * 8 + (tid >> 5);
  int l = tid & 31;
  int tt = (int)(row >> 8);
  int b  = (int)(row & 255);
  int grp = b >> 4, r = b & 15;
  float pv = 0.f;
  if (l < 8) pv = cpart[(((size_t)tt * 16 + grp) * 16 + r) * 8 + l];
  pv += __shfl_down(pv, 4, 8); pv += __shfl_down(pv, 2, 8); pv += __shfl_down(pv, 1, 8);
  float ce = __shfl(pv, 0, 32) * EPSF;
  float* po = out + row * SS + l * 8;
  const float* pb = beta + row * SS + l * 8;
  float4 v0 = *reinterpret_cast<const float4*>(po);
  float4 v1 = *reinterpret_cast<const float4*>(po + 4);
  float4 b0 = *reinterpret_cast<const float4*>(pb);
  float4 b1 = *reinterpret_cast<const float4*>(pb + 4);
  float z[8];
  z[0] = __logf(v0.x + ce) + __logf(b0.x);
  z[1] = __logf(v0.y + ce) + __logf(b0.y);
  z[2] = __logf(v0.z + ce) + __logf(b0.z);
  z[3] = __logf(v0.w + ce) + __logf(b0.w);
  z[4] = __logf(v1.x + ce) + __logf(b1.x);
  z[5] = __logf(v1.y + ce) + __logf(b1.y);
  z[6] = __logf(v1.z + ce) + __logf(b1.z);
  z[7] = __logf(v1.w + ce) + __logf(b1.w);
  float m = z[0];
  #pragma unroll
  for (int k = 1; k < 8; ++k) m = fmaxf(m, z[k]);
  #pragma unroll
  for (int o = 16; o >= 1; o >>= 1) m = fmaxf(m, __shfl_xor(m, o, 32));
  float e[8]; float s = 0.f;
  #pragma unroll
  for (int k = 0; k < 8; ++k) { e[k] = __expf(z[k] - m); s += e[k]; }
  #pragma unroll
  for (int o = 16; o >= 1; o >>= 1) s += __shfl_xor(s, o, 32);
  float inv = 1.0f / s;
  *reinterpret_cast<float4*>(po)     = make_float4(e[0]*inv, e[1]*inv, e[2]*inv, e[3]*inv);
  *reinterpret_cast<float4*>(po + 4) = make_float4(e[4]*inv, e[5]*inv, e[6]*inv, e[7]*inv);
}

extern "C" void kernel_launch(void* const* d_in, const int* in_sizes, int n_in,
                              void* d_out, int out_size, void* d_ws, size_t ws_size,
                              hipStream_t stream) {
  (void)in_sizes; (void)n_in; (void)out_size;
  const float* x   = (const float*)d_in[0];
  const float* a   = (const float*)d_in[1];
  const float* msk = (const float*)d_in[2];
  const float* mu  = (const float*)d_in[3];
  const float* lv  = (const float*)d_in[4];
  const float* wl  = (const float*)d_in[5];
  const float* s0  = (const float*)d_in[6];
  float* out = (float*)d_out;

  char* ws = (char*)d_ws;
  float* logp  = (float*)ws;  ws += (size_t)TT * BB * SS * 4;
  float* beta  = (float*)ws;  ws += (size_t)TT * BB * SS * 4;
  float* Mmax  = (float*)ws;  ws += (size_t)TT * BB * 4;
  float* cpart = (float*)ws;  ws += (size_t)TT * BB * 8 * 4;   // [T][16][16][8]
  ushort_t* Wf = (ushort_t*)ws; ws += (size_t)AA * SS * SS * 2;
  ushort_t* Wb = (ushort_t*)ws; ws += (size_t)AA * SS * SS * 2;
  float* A1 = (float*)ws;    ws += (size_t)SS * DD * 4;
  float* A2 = (float*)ws;    ws += (size_t)SS * DD * 4;
  float* Cs = (float*)ws;    ws += 1024;
  float* lp0 = (float*)ws;   ws += 1024;
  unsigned* amb = (unsigned*)ws; ws += (size_t)2 * 16 * 16 * 256 * 4;  // 512 KB
  unsigned* bmb = (unsigned*)ws; ws += (size_t)2 * 16 * 16 * 256 * 4;  // 512 KB
  unsigned* cmb = (unsigned*)ws; ws += (size_t)2 * 16 * 16 * 8 * 4;    // 16 KB
  unsigned* rmb = (unsigned*)ws; ws += (size_t)2 * 16 * 16 * 8 * 4;    // 16 KB
  if (ws_size < (size_t)(ws - (char*)d_ws)) return;

  // invalidate all mailbox tags (0xFFFF != any step tag)
  hipMemsetAsync(amb, 0xFF, (size_t)(2 * 16 * 16 * 256 * 4) * 2 + (size_t)(2 * 16 * 16 * 8 * 4) * 2, stream);

  k_params<<<SS, DD, 0, stream>>>(mu, lv, A1, A2, Cs);
  k_pi0<<<1, SS, 0, stream>>>(s0, lp0);
  k_trans<<<256, 256, 0, stream>>>(wl, Wf, Wb);
  k_logp<<<TT * BB / 32, 256, 0, stream>>>(x, A1, A2, Cs, logp, Mmax);
  k_recur<<<256, 256, 0, stream>>>(a, msk, out, beta, logp, Mmax, cpart, Wf, Wb, lp0,
                                   amb, bmb, cmb, rmb);
  k_qz<<<TT * BB / 8, 256, 0, stream>>>(out, beta, cpart);
}